// Round 9
// baseline (129.888 us; speedup 1.0000x reference)
//
#include <hip/hip_runtime.h>
#include <hip/hip_fp16.h>

// BackProjectionLinear: out[b,p] = sum_d apod[d] * lerp(sino[b,d], k[p,d], a[p,d]) / 63.5
// B=4, N_DET=128, N_T=2048, pixels=65536.
//
// R9: R4(16 waves/CU)=49.5us vs R8(32 waves/CU)=48us -> TLP is NOT the
// limiter. Invariant across both: 4.19M same-address device-scope atomics,
// WRITE_SIZE = 16.4MB = 4B x 4.19M (out-lines written back ~16x) -> the
// atomic RMW pipe is the suspected floor. Discriminating change: replace
// atomics with non-atomic coalesced partial stores to d_ws[octet][b][px]
// (16MB) + a reduce kernel (16MB read + 1MB write, ~3us). Main kernel body
// is R8 unchanged (48 VGPR, no spill, 32KB LDS, 4 phases).

#define NB      4
#define NDET    128
#define NT      2048
#define NPIX    65536
#define NOCT    16
#define DBLOCK  8                    // dets per block = one 64B lut line
#define DPH     4                    // dets per phase (det-half)
#define NPHASE  4                    // (batch-pair) x (det-half)
#define PTILE   1024
#define THREADS 512
#define PXPT    (PTILE / THREADS)    // 2 pixels per thread

template<bool USE_WS>
__global__ __launch_bounds__(THREADS, 4)
void bp_kernel(const float* __restrict__ sino,
               const float* __restrict__ lut,
               float* __restrict__ dst) {   // USE_WS ? ws partials : out (atomic)
    // [dl (0..3)][t] half2 = (b_even, b_odd) for the current batch-pair. 32 KB.
    __shared__ __half2 lds[DPH][NT];

    const int tid   = threadIdx.x;
    const int octet = blockIdx.x & 15;   // bid%8 ~ XCD pinning
    const int tile  = blockIdx.x >> 4;   // 0..63
    const int d0    = octet * DBLOCK;
    const int px0   = tile * PTILE;

    float apod[DBLOCK];
#pragma unroll
    for (int j = 0; j < DBLOCK; ++j) {
        float x = (float)(d0 + j) * (6.28318530717958647692f / 127.0f);
        apod[j] = 0.5f - 0.5f * __cosf(x);
    }

    // ---- full 64B lut line per pixel, loaded once (32 VGPRs) ----
    float4 L[PXPT][4];   // L[i][q] = (k,a) for dets d0+2q, d0+2q+1
#pragma unroll
    for (int i = 0; i < PXPT; ++i) {
        const float4* lp = (const float4*)
            (lut + ((size_t)(px0 + tid + i * THREADS) * NDET + d0) * 2);
#pragma unroll
        for (int q = 0; q < 4; ++q) L[i][q] = lp[q];
    }

    float acc[PXPT][NB];
#pragma unroll
    for (int i = 0; i < PXPT; ++i)
#pragma unroll
        for (int b = 0; b < NB; ++b) acc[i][b] = 0.0f;

    const float4* s4 = (const float4*)sino;

    for (int ph = 0; ph < NPHASE; ++ph) {
        const int bp  = ph >> 1;          // batch pair: batches 2bp, 2bp+1
        const int dh  = ph & 1;           // det half
        const int b0  = bp * 2;
        const int dg0 = d0 + dh * DPH;
        if (ph) __syncthreads();          // prior-phase readers done

        // ---- stage 4 dets x 2 batches x 2048 t as half2 ----
        for (int f = tid; f < DPH * (NT / 4); f += THREADS) {
            int dl = f >> 9;              // 0..3
            int t4 = f & 511;
            size_t row = ((size_t)b0 * NDET + dg0 + dl) * (NT / 4) + t4;
            float4 ve = s4[row];
            float4 vo = s4[row + (size_t)NDET * (NT / 4)];
            __half2* dstp = &lds[dl][t4 * 4];
            dstp[0] = __floats2half2_rn(ve.x, vo.x);
            dstp[1] = __floats2half2_rn(ve.y, vo.y);
            dstp[2] = __floats2half2_rn(ve.z, vo.z);
            dstp[3] = __floats2half2_rn(ve.w, vo.w);
        }
        __syncthreads();

        // ---- gather: 4 dets x 2 px/thread ----
#pragma unroll
        for (int i = 0; i < PXPT; ++i) {
#pragma unroll
            for (int q2 = 0; q2 < 2; ++q2) {
                float4 Lq = L[i][dh * 2 + q2];
#pragma unroll
                for (int h = 0; h < 2; ++h) {
                    float kf = h ? Lq.z : Lq.x;
                    float af = h ? Lq.w : Lq.y;
                    int   dl = q2 * 2 + h;
                    int k = (int)kf;
                    bool valid = (unsigned)k < (unsigned)(NT - 1);
                    float w  = valid ? apod[dh * DPH + dl] : 0.0f;
                    int  k0  = valid ? k : 0;
                    __half2 s0v = lds[dl][k0];
                    __half2 s1v = lds[dl][k0 + 1];
                    __half2 a2  = __float2half2_rn(af);
                    __half2 sk  = __hfma2(a2, __hsub2(s1v, s0v), s0v);
                    float2  fv  = __half22float2(sk);
                    acc[i][b0 + 0] = fmaf(w, fv.x, acc[i][b0 + 0]);
                    acc[i][b0 + 1] = fmaf(w, fv.y, acc[i][b0 + 1]);
                }
            }
        }
    }

    // ---- emit ----
    if (USE_WS) {
        // non-atomic coalesced partial: ws[octet][b][px]
#pragma unroll
        for (int i = 0; i < PXPT; ++i) {
            const int px = px0 + tid + i * THREADS;
#pragma unroll
            for (int b = 0; b < NB; ++b)
                dst[((size_t)(octet * NB + b) * NPIX) + px] = acc[i][b];
        }
    } else {
        const float inv_norm = 1.0f / 63.5f;
#pragma unroll
        for (int i = 0; i < PXPT; ++i) {
            const int px = px0 + tid + i * THREADS;
#pragma unroll
            for (int b = 0; b < NB; ++b)
                atomicAdd(&dst[(size_t)b * NPIX + px], acc[i][b] * inv_norm);
        }
    }
}

// out[b][px] = inv_norm * sum_o ws[o][b][px]; one float4 per thread.
__global__ __launch_bounds__(256)
void reduce_kernel(const float* __restrict__ part, float* __restrict__ out) {
    const int j = blockIdx.x * 256 + threadIdx.x;   // float4 index, 65536 total
    const float4* p4 = (const float4*)part;
    float4 s = p4[j];
#pragma unroll
    for (int o = 1; o < NOCT; ++o) {
        float4 v = p4[(size_t)o * (NB * NPIX / 4) + j];
        s.x += v.x; s.y += v.y; s.z += v.z; s.w += v.w;
    }
    const float inv_norm = 1.0f / 63.5f;
    float4 r;
    r.x = s.x * inv_norm; r.y = s.y * inv_norm;
    r.z = s.z * inv_norm; r.w = s.w * inv_norm;
    ((float4*)out)[j] = r;
}

extern "C" void kernel_launch(void* const* d_in, const int* in_sizes, int n_in,
                              void* d_out, int out_size, void* d_ws, size_t ws_size,
                              hipStream_t stream) {
    const float* sino = (const float*)d_in[0];
    const float* lut  = (const float*)d_in[1];
    float* out = (float*)d_out;

    const size_t ws_needed = (size_t)NOCT * NB * NPIX * sizeof(float);  // 16 MB
    if (ws_size >= ws_needed) {
        float* part = (float*)d_ws;
        bp_kernel<true><<<dim3(1024), dim3(THREADS), 0, stream>>>(sino, lut, part);
        reduce_kernel<<<dim3(NB * NPIX / 4 / 256), dim3(256), 0, stream>>>(part, out);
    } else {
        (void)hipMemsetAsync(d_out, 0, (size_t)out_size * sizeof(float), stream);
        bp_kernel<false><<<dim3(1024), dim3(THREADS), 0, stream>>>(sino, lut, out);
    }
}

// Round 10
// 124.334 us; speedup vs baseline: 1.0447x; 1.0447x over previous
//
#include <hip/hip_runtime.h>
#include <hip/hip_fp16.h>

// BackProjectionLinear: out[b,p] = sum_d apod[d] * lerp(sino[b,d], k[p,d], a[p,d]) / 63.5
// B=4, N_DET=128, N_T=2048, pixels=65536.
//
// R10: R9 proved atomics are NOT the limiter (ws-stores == atomics == 49us).
// The 49us invariant is the phase-loop work: fp32 staging (2x per det row,
// heavy cvt VALU) + 2x LDS decode per (px,det). Fix at the source:
//  - cvt_kernel pre-packs sino once: ws16[det][t] = 4x half (b0..b3) in 8B.
//  - bp stages each det row ONCE for all 4 batches (pure uint4 copy, no cvt,
//    staging traffic halved), 4 phases x 2 dets x 8KB = 32KB LDS.
//  - gather decodes each (px,det) lut entry once for all 4 batches:
//    one 8B-entry pair (ds_read2_b64) + 2x hfma2 -> 4 batch MACs.
//  - Everything measured-clean kept: lut 64B line in regs (read once),
//    launch_bounds(512,4) (R8: 48 VGPR, no spill), atomic emit, octet->XCD.

#define NB      4
#define NDET    128
#define NT      2048
#define NPIX    65536
#define DBLOCK  8                    // dets per block = one 64B lut line
#define DPH     2                    // dets per phase
#define NPHASE  4
#define PTILE   1024
#define THREADS 512
#define PXPT    (PTILE / THREADS)    // 2 pixels per thread

// ---- pass 1: sino fp32[4][128][2048] -> ws16[det][t] = (h0,h1,h2,h3) 8B ----
__global__ __launch_bounds__(256)
void cvt_kernel(const float* __restrict__ sino, uint2* __restrict__ ws16) {
    const int id = blockIdx.x * 256 + threadIdx.x;     // det*NT + t
    float v0 = sino[id];
    float v1 = sino[id + NDET * NT];
    float v2 = sino[id + 2 * NDET * NT];
    float v3 = sino[id + 3 * NDET * NT];
    __half2 h01 = __floats2half2_rn(v0, v1);
    __half2 h23 = __floats2half2_rn(v2, v3);
    uint2 u;
    u.x = *(const unsigned*)&h01;
    u.y = *(const unsigned*)&h23;
    ws16[id] = u;
}

__global__ __launch_bounds__(THREADS, 4)
void bp_kernel(const uint2* __restrict__ ws16,
               const float* __restrict__ lut,
               float* __restrict__ out) {
    // [dl (0..1)][t] : 8B = 4 batches fp16. 32 KB.
    __shared__ uint2 lds2[DPH * NT];

    const int tid   = threadIdx.x;
    const int octet = blockIdx.x & 15;   // bid%8 ~ XCD pinning
    const int tile  = blockIdx.x >> 4;   // 0..63
    const int d0    = octet * DBLOCK;
    const int px0   = tile * PTILE;

    float apod[DBLOCK];
#pragma unroll
    for (int j = 0; j < DBLOCK; ++j) {
        float x = (float)(d0 + j) * (6.28318530717958647692f / 127.0f);
        apod[j] = 0.5f - 0.5f * __cosf(x);
    }

    // ---- full 64B lut line per pixel, loaded once (32 VGPRs) ----
    // L[i][q] = (k,a) for dets d0+2q, d0+2q+1; phase ph consumes L[i][ph].
    float4 L[PXPT][NPHASE];
#pragma unroll
    for (int i = 0; i < PXPT; ++i) {
        const float4* lp = (const float4*)
            (lut + ((size_t)(px0 + tid + i * THREADS) * NDET + d0) * 2);
#pragma unroll
        for (int q = 0; q < NPHASE; ++q) L[i][q] = lp[q];
    }

    float acc[PXPT][NB];
#pragma unroll
    for (int i = 0; i < PXPT; ++i)
#pragma unroll
        for (int b = 0; b < NB; ++b) acc[i][b] = 0.0f;

    for (int ph = 0; ph < NPHASE; ++ph) {
        const int dg0 = d0 + ph * DPH;
        if (ph) __syncthreads();          // prior-phase readers done

        // ---- stage: pure contiguous copy, 2 dets x 16KB, no conversion ----
        // 2048 uint4 items -> 4 iters/thread: global uint4 load + ds_write_b128.
        {
            const uint4* src = (const uint4*)(ws16 + (size_t)dg0 * NT);
            uint4* dst = (uint4*)lds2;
            for (int f = tid; f < DPH * NT / 2; f += THREADS)
                dst[f] = src[f];
        }
        __syncthreads();

        // ---- gather: 2 dets x 2 px/thread; ONE decode per (px,det),
        //      one 8B entry pair covers all 4 batches ----
#pragma unroll
        for (int i = 0; i < PXPT; ++i) {
            float4 Lq = L[i][ph];
#pragma unroll
            for (int h = 0; h < 2; ++h) {
                float kf = h ? Lq.z : Lq.x;
                float af = h ? Lq.w : Lq.y;
                int k = (int)kf;
                bool valid = (unsigned)k < (unsigned)(NT - 1);
                float w  = valid ? apod[ph * DPH + h] : 0.0f;
                int  k0  = valid ? k : 0;
                uint2 e0 = lds2[h * NT + k0];
                uint2 e1 = lds2[h * NT + k0 + 1];
                __half2 a01 = *(__half2*)&e0.x, a23 = *(__half2*)&e0.y;
                __half2 b01 = *(__half2*)&e1.x, b23 = *(__half2*)&e1.y;
                __half2 a2  = __float2half2_rn(af);
                __half2 s01 = __hfma2(a2, __hsub2(b01, a01), a01);
                __half2 s23 = __hfma2(a2, __hsub2(b23, a23), a23);
                float2 f01 = __half22float2(s01);
                float2 f23 = __half22float2(s23);
                acc[i][0] = fmaf(w, f01.x, acc[i][0]);
                acc[i][1] = fmaf(w, f01.y, acc[i][1]);
                acc[i][2] = fmaf(w, f23.x, acc[i][2]);
                acc[i][3] = fmaf(w, f23.y, acc[i][3]);
            }
        }
    }

    // ---- emit partial sums (16 octet-blocks contribute per output) ----
    const float inv_norm = 1.0f / 63.5f;   // sum(apod) == 63.5 exactly
#pragma unroll
    for (int i = 0; i < PXPT; ++i) {
        const int px = px0 + tid + i * THREADS;
#pragma unroll
        for (int b = 0; b < NB; ++b) {
            atomicAdd(&out[(size_t)b * NPIX + px], acc[i][b] * inv_norm);
        }
    }
}

// ---- fallback (ws too small): exact R8 kernel, fp32 staging + cvt ----
__global__ __launch_bounds__(THREADS, 4)
void bp_fallback(const float* __restrict__ sino,
                 const float* __restrict__ lut,
                 float* __restrict__ out) {
    __shared__ __half2 lds[4][NT];
    const int tid   = threadIdx.x;
    const int octet = blockIdx.x & 15;
    const int tile  = blockIdx.x >> 4;
    const int d0    = octet * DBLOCK;
    const int px0   = tile * PTILE;
    float apod[DBLOCK];
#pragma unroll
    for (int j = 0; j < DBLOCK; ++j) {
        float x = (float)(d0 + j) * (6.28318530717958647692f / 127.0f);
        apod[j] = 0.5f - 0.5f * __cosf(x);
    }
    float4 L[PXPT][4];
#pragma unroll
    for (int i = 0; i < PXPT; ++i) {
        const float4* lp = (const float4*)
            (lut + ((size_t)(px0 + tid + i * THREADS) * NDET + d0) * 2);
#pragma unroll
        for (int q = 0; q < 4; ++q) L[i][q] = lp[q];
    }
    float acc[PXPT][NB];
#pragma unroll
    for (int i = 0; i < PXPT; ++i)
#pragma unroll
        for (int b = 0; b < NB; ++b) acc[i][b] = 0.0f;
    const float4* s4 = (const float4*)sino;
    for (int ph = 0; ph < 4; ++ph) {
        const int b0  = (ph >> 1) * 2;
        const int dh  = ph & 1;
        const int dg0 = d0 + dh * 4;
        if (ph) __syncthreads();
        for (int f = tid; f < 4 * (NT / 4); f += THREADS) {
            int dl = f >> 9;
            int t4 = f & 511;
            size_t row = ((size_t)b0 * NDET + dg0 + dl) * (NT / 4) + t4;
            float4 ve = s4[row];
            float4 vo = s4[row + (size_t)NDET * (NT / 4)];
            __half2* dstp = &lds[dl][t4 * 4];
            dstp[0] = __floats2half2_rn(ve.x, vo.x);
            dstp[1] = __floats2half2_rn(ve.y, vo.y);
            dstp[2] = __floats2half2_rn(ve.z, vo.z);
            dstp[3] = __floats2half2_rn(ve.w, vo.w);
        }
        __syncthreads();
#pragma unroll
        for (int i = 0; i < PXPT; ++i) {
#pragma unroll
            for (int q2 = 0; q2 < 2; ++q2) {
                float4 Lq = L[i][dh * 2 + q2];
#pragma unroll
                for (int h = 0; h < 2; ++h) {
                    float kf = h ? Lq.z : Lq.x;
                    float af = h ? Lq.w : Lq.y;
                    int   dl = q2 * 2 + h;
                    int k = (int)kf;
                    bool valid = (unsigned)k < (unsigned)(NT - 1);
                    float w  = valid ? apod[dh * 4 + dl] : 0.0f;
                    int  k0  = valid ? k : 0;
                    __half2 s0v = lds[dl][k0];
                    __half2 s1v = lds[dl][k0 + 1];
                    __half2 a2  = __float2half2_rn(af);
                    __half2 sk  = __hfma2(a2, __hsub2(s1v, s0v), s0v);
                    float2  fv  = __half22float2(sk);
                    acc[i][b0 + 0] = fmaf(w, fv.x, acc[i][b0 + 0]);
                    acc[i][b0 + 1] = fmaf(w, fv.y, acc[i][b0 + 1]);
                }
            }
        }
    }
    const float inv_norm = 1.0f / 63.5f;
#pragma unroll
    for (int i = 0; i < PXPT; ++i) {
        const int px = px0 + tid + i * THREADS;
#pragma unroll
        for (int b = 0; b < NB; ++b)
            atomicAdd(&out[(size_t)b * NPIX + px], acc[i][b] * inv_norm);
    }
}

extern "C" void kernel_launch(void* const* d_in, const int* in_sizes, int n_in,
                              void* d_out, int out_size, void* d_ws, size_t ws_size,
                              hipStream_t stream) {
    const float* sino = (const float*)d_in[0];
    const float* lut  = (const float*)d_in[1];
    float* out = (float*)d_out;

    (void)hipMemsetAsync(d_out, 0, (size_t)out_size * sizeof(float), stream);

    const size_t ws_needed = (size_t)NDET * NT * sizeof(uint2);   // 2 MB
    if (ws_size >= ws_needed) {
        uint2* ws16 = (uint2*)d_ws;
        cvt_kernel<<<dim3(NDET * NT / 256), dim3(256), 0, stream>>>(sino, ws16);
        bp_kernel<<<dim3(1024), dim3(THREADS), 0, stream>>>(ws16, lut, out);
    } else {
        bp_fallback<<<dim3(1024), dim3(THREADS), 0, stream>>>(sino, lut, out);
    }
}

// Round 11
// 123.600 us; speedup vs baseline: 1.0509x; 1.0059x over previous
//
#include <hip/hip_runtime.h>
#include <hip/hip_fp16.h>

// BackProjectionLinear: out[b,p] = sum_d apod[d] * lerp(sino[b,d], k[p,d], a[p,d]) / 63.5
// B=4, N_DET=128, N_T=2048, pixels=65536.
//
// R11: R10's 43.5us = serial ~10us lut burst (all blocks front-load their
// lut lines; LDS idle) + ~13us/CU LDS gather pipe (random b64 reads ~3-4x
// conflict cost) + barrier lockstep preventing overlap. Restructure:
//  - Block = octet x 2048 px, 1024 threads, PXPT=2. TWO quartet phases
//    (4 dets x 2048 t x 8B fp16-packed = 64KB LDS each), 3 barriers total.
//  - lut line halves: first half loaded up front, SECOND half issued right
//    after phase A's stage-barrier and consumed in phase B -> drains under
//    gather A. Lut streaming overlaps LDS gather work by construction.
//  - ws16 pre-pack (R10): 8B = 4 batches fp16 -> stage is a pure uint4 copy,
//    one 8B LDS entry covers all 4 batches per gather.
//  - VGPR envelope: Lcur 16 + Lnext 16 + acc 8 ~ 80, cap 128 via
//    launch_bounds(1024,4). WRITE_SIZE is the spill canary (16.4MB = clean).
//  - atomic emit (R9 proved atomics == stores), 16 octet-blocks per output.

#define NB      4
#define NDET    128
#define NT      2048
#define NPIX    65536
#define DBLOCK  8                    // dets per block = one 64B lut line
#define DQ      4                    // dets per quartet phase
#define PTILE   2048
#define THREADS 1024
#define PXPT    (PTILE / THREADS)    // 2 pixels per thread

// ---- pass 1: sino fp32[4][128][2048] -> ws16[det][t] = (h0,h1,h2,h3) 8B ----
__global__ __launch_bounds__(256)
void cvt_kernel(const float* __restrict__ sino, uint2* __restrict__ ws16) {
    const int id = blockIdx.x * 256 + threadIdx.x;     // det*NT + t
    float v0 = sino[id];
    float v1 = sino[id + NDET * NT];
    float v2 = sino[id + 2 * NDET * NT];
    float v3 = sino[id + 3 * NDET * NT];
    __half2 h01 = __floats2half2_rn(v0, v1);
    __half2 h23 = __floats2half2_rn(v2, v3);
    uint2 u;
    u.x = *(const unsigned*)&h01;
    u.y = *(const unsigned*)&h23;
    ws16[id] = u;
}

__global__ __launch_bounds__(THREADS, 4)
void bp_kernel(const uint2* __restrict__ ws16,
               const float* __restrict__ lut,
               float* __restrict__ out) {
    // one quartet: [dl (0..3)][t] 8B = 4 batches fp16. 64 KB.
    __shared__ uint2 lds2[DQ * NT];

    const int tid   = threadIdx.x;
    const int octet = blockIdx.x & 15;   // bid%8 ~ XCD pinning
    const int tile  = blockIdx.x >> 4;   // 0..31
    const int d0    = octet * DBLOCK;
    const int px0   = tile * PTILE;

    float apod[DBLOCK];
#pragma unroll
    for (int j = 0; j < DBLOCK; ++j) {
        float x = (float)(d0 + j) * (6.28318530717958647692f / 127.0f);
        apod[j] = 0.5f - 0.5f * __cosf(x);
    }

    float acc[PXPT][NB];
#pragma unroll
    for (int i = 0; i < PXPT; ++i)
#pragma unroll
        for (int b = 0; b < NB; ++b) acc[i][b] = 0.0f;

    // lut pointers per pixel (first 32B of the 64B line = quartet 0)
    const float4* lp[PXPT];
#pragma unroll
    for (int i = 0; i < PXPT; ++i)
        lp[i] = (const float4*)
            (lut + ((size_t)(px0 + tid + i * THREADS) * NDET + d0) * 2);

    // ---- lut quartet-0 halves (16 VGPR) ----
    float4 Lcur[PXPT][2];
#pragma unroll
    for (int i = 0; i < PXPT; ++i) {
        Lcur[i][0] = lp[i][0];
        Lcur[i][1] = lp[i][1];
    }

    // ---- stage quartet 0: pure 64KB copy, 4 uint4/thread ----
    {
        const uint4* src = (const uint4*)(ws16 + (size_t)d0 * NT);
        uint4* dst = (uint4*)lds2;
#pragma unroll
        for (int r = 0; r < 4; ++r) dst[tid + r * THREADS] = src[tid + r * THREADS];
    }
    __syncthreads();                  // quartet 0 ready

    // ---- issue lut quartet-1 halves; drain under gather A ----
    float4 Lnext[PXPT][2];
#pragma unroll
    for (int i = 0; i < PXPT; ++i) {
        Lnext[i][0] = lp[i][2];
        Lnext[i][1] = lp[i][3];
    }

    // gather over one quartet; Lq[i][0..1] = (k,a) pairs for 4 dets
    auto gather = [&](const float4 (*Lq)[2], int jbase) {
#pragma unroll
        for (int i = 0; i < PXPT; ++i) {
#pragma unroll
            for (int q = 0; q < 2; ++q) {
                float4 Le = Lq[i][q];
#pragma unroll
                for (int h = 0; h < 2; ++h) {
                    float kf = h ? Le.z : Le.x;
                    float af = h ? Le.w : Le.y;
                    int   dl = q * 2 + h;
                    int k = (int)kf;
                    bool valid = (unsigned)k < (unsigned)(NT - 1);
                    float w  = valid ? apod[jbase + dl] : 0.0f;
                    int  k0  = valid ? k : 0;
                    uint2 e0 = lds2[dl * NT + k0];
                    uint2 e1 = lds2[dl * NT + k0 + 1];
                    __half2 a01 = *(__half2*)&e0.x, a23 = *(__half2*)&e0.y;
                    __half2 b01 = *(__half2*)&e1.x, b23 = *(__half2*)&e1.y;
                    __half2 a2  = __float2half2_rn(af);
                    __half2 s01 = __hfma2(a2, __hsub2(b01, a01), a01);
                    __half2 s23 = __hfma2(a2, __hsub2(b23, a23), a23);
                    float2 f01 = __half22float2(s01);
                    float2 f23 = __half22float2(s23);
                    acc[i][0] = fmaf(w, f01.x, acc[i][0]);
                    acc[i][1] = fmaf(w, f01.y, acc[i][1]);
                    acc[i][2] = fmaf(w, f23.x, acc[i][2]);
                    acc[i][3] = fmaf(w, f23.y, acc[i][3]);
                }
            }
        }
    };

    gather(Lcur, 0);                  // quartet 0 (dets d0..d0+3)
    __syncthreads();                  // gather A done before overwrite

    // ---- stage quartet 1 ----
    {
        const uint4* src = (const uint4*)(ws16 + (size_t)(d0 + DQ) * NT);
        uint4* dst = (uint4*)lds2;
#pragma unroll
        for (int r = 0; r < 4; ++r) dst[tid + r * THREADS] = src[tid + r * THREADS];
    }
    __syncthreads();                  // quartet 1 ready

    gather(Lnext, DQ);                // quartet 1 (dets d0+4..d0+7)

    // ---- emit partial sums (16 octet-blocks contribute per output) ----
    const float inv_norm = 1.0f / 63.5f;   // sum(apod) == 63.5 exactly
#pragma unroll
    for (int i = 0; i < PXPT; ++i) {
        const int px = px0 + tid + i * THREADS;
#pragma unroll
        for (int b = 0; b < NB; ++b) {
            atomicAdd(&out[(size_t)b * NPIX + px], acc[i][b] * inv_norm);
        }
    }
}

// ---- fallback (ws too small): R8 kernel, fp32 staging + cvt in-kernel ----
__global__ __launch_bounds__(512, 4)
void bp_fallback(const float* __restrict__ sino,
                 const float* __restrict__ lut,
                 float* __restrict__ out) {
    __shared__ __half2 lds[4][NT];
    const int tid   = threadIdx.x;
    const int octet = blockIdx.x & 15;
    const int tile  = blockIdx.x >> 4;
    const int d0    = octet * DBLOCK;
    const int px0   = tile * 1024;
    float apod[DBLOCK];
#pragma unroll
    for (int j = 0; j < DBLOCK; ++j) {
        float x = (float)(d0 + j) * (6.28318530717958647692f / 127.0f);
        apod[j] = 0.5f - 0.5f * __cosf(x);
    }
    float4 L[2][4];
#pragma unroll
    for (int i = 0; i < 2; ++i) {
        const float4* lq = (const float4*)
            (lut + ((size_t)(px0 + tid + i * 512) * NDET + d0) * 2);
#pragma unroll
        for (int q = 0; q < 4; ++q) L[i][q] = lq[q];
    }
    float acc[2][NB];
#pragma unroll
    for (int i = 0; i < 2; ++i)
#pragma unroll
        for (int b = 0; b < NB; ++b) acc[i][b] = 0.0f;
    const float4* s4 = (const float4*)sino;
    for (int ph = 0; ph < 4; ++ph) {
        const int b0  = (ph >> 1) * 2;
        const int dh  = ph & 1;
        const int dg0 = d0 + dh * 4;
        if (ph) __syncthreads();
        for (int f = tid; f < 4 * (NT / 4); f += 512) {
            int dl = f >> 9;
            int t4 = f & 511;
            size_t row = ((size_t)b0 * NDET + dg0 + dl) * (NT / 4) + t4;
            float4 ve = s4[row];
            float4 vo = s4[row + (size_t)NDET * (NT / 4)];
            __half2* dstp = &lds[dl][t4 * 4];
            dstp[0] = __floats2half2_rn(ve.x, vo.x);
            dstp[1] = __floats2half2_rn(ve.y, vo.y);
            dstp[2] = __floats2half2_rn(ve.z, vo.z);
            dstp[3] = __floats2half2_rn(ve.w, vo.w);
        }
        __syncthreads();
#pragma unroll
        for (int i = 0; i < 2; ++i) {
#pragma unroll
            for (int q2 = 0; q2 < 2; ++q2) {
                float4 Lq = L[i][dh * 2 + q2];
#pragma unroll
                for (int h = 0; h < 2; ++h) {
                    float kf = h ? Lq.z : Lq.x;
                    float af = h ? Lq.w : Lq.y;
                    int   dl = q2 * 2 + h;
                    int k = (int)kf;
                    bool valid = (unsigned)k < (unsigned)(NT - 1);
                    float w  = valid ? apod[dh * 4 + dl] : 0.0f;
                    int  k0  = valid ? k : 0;
                    __half2 s0v = lds[dl][k0];
                    __half2 s1v = lds[dl][k0 + 1];
                    __half2 a2  = __float2half2_rn(af);
                    __half2 sk  = __hfma2(a2, __hsub2(s1v, s0v), s0v);
                    float2  fv  = __half22float2(sk);
                    acc[i][b0 + 0] = fmaf(w, fv.x, acc[i][b0 + 0]);
                    acc[i][b0 + 1] = fmaf(w, fv.y, acc[i][b0 + 1]);
                }
            }
        }
    }
    const float inv_norm = 1.0f / 63.5f;
#pragma unroll
    for (int i = 0; i < 2; ++i) {
        const int px = px0 + tid + i * 512;
#pragma unroll
        for (int b = 0; b < NB; ++b)
            atomicAdd(&out[(size_t)b * NPIX + px], acc[i][b] * inv_norm);
    }
}

extern "C" void kernel_launch(void* const* d_in, const int* in_sizes, int n_in,
                              void* d_out, int out_size, void* d_ws, size_t ws_size,
                              hipStream_t stream) {
    const float* sino = (const float*)d_in[0];
    const float* lut  = (const float*)d_in[1];
    float* out = (float*)d_out;

    (void)hipMemsetAsync(d_out, 0, (size_t)out_size * sizeof(float), stream);

    const size_t ws_needed = (size_t)NDET * NT * sizeof(uint2);   // 2 MB
    if (ws_size >= ws_needed) {
        uint2* ws16 = (uint2*)d_ws;
        cvt_kernel<<<dim3(NDET * NT / 256), dim3(256), 0, stream>>>(sino, ws16);
        // 16 octets x 32 tiles = 512 blocks x 1024 thr (1 block/CU, 2 rounds)
        bp_kernel<<<dim3(512), dim3(THREADS), 0, stream>>>(ws16, lut, out);
    } else {
        bp_fallback<<<dim3(1024), dim3(512), 0, stream>>>(sino, lut, out);
    }
}